// Round 1
// baseline (6607.640 us; speedup 1.0000x reference)
//
#include <hip/hip_runtime.h>

// SequentialChart: ops are all < START(256); writes go to rows >= 256, so all
// 128 "sequential" steps are independent. One big gathered GEMM
// (131072 x 2048) @ (2048 x 5120) in bf16 MFMA + gates + per-(s,b) softmax
// combine. Chunked 8 steps per launch to bound workspace (68 MB total).

typedef unsigned int u32;
typedef unsigned short u16;
typedef __attribute__((ext_vector_type(8))) short short8;
typedef __attribute__((ext_vector_type(4))) float f32x4;
typedef __attribute__((ext_vector_type(4))) u16 u16x4;

#define CHART_ROWS 384
#define CH_STEPS 8            // steps per chunk launch
#define RCHUNK (CH_STEPS*32*32)   // 8192 rows per chunk
#define BM 64
#define BG 64
#define BK 32

__device__ __forceinline__ u16 f2bf(float f) {           // fp32 -> bf16 RNE
  u32 u = __float_as_uint(f);
  u32 r = u + 0x7fffu + ((u >> 16) & 1u);
  return (u16)(r >> 16);
}
__device__ __forceinline__ float bf2f(u16 v) { return __uint_as_float(((u32)v) << 16); }
// overflow-safe: exp(inf) -> rcp -> 0, no NaN
__device__ __forceinline__ float fast_sigmoid(float x) { return __builtin_amdgcn_rcpf(1.0f + __expf(-x)); }
__device__ __forceinline__ float fast_tanh(float x)    { return 1.0f - 2.0f * __builtin_amdgcn_rcpf(1.0f + __expf(2.0f * x)); }

__device__ __forceinline__ void async16(const void* g, void* l) {
  __builtin_amdgcn_global_load_lds((const __attribute__((address_space(1))) u32*)g,
                                   (__attribute__((address_space(3))) u32*)l, 16, 0, 0);
}

// ---- U (5120x2048 fp32) -> bf16, same row-major layout
__global__ void k_cvt_u(const float4* __restrict__ U4, u16* __restrict__ Ubf) {
  int i = blockIdx.x * blockDim.x + threadIdx.x;   // 2,621,440 threads
  float4 v = U4[i];
  u16x4 o = {f2bf(v.x), f2bf(v.y), f2bf(v.z), f2bf(v.w)};
  *(u16x4*)(Ubf + (size_t)i * 4) = o;
}

// ---- chart[b][op<256][1024:2048] -> bf16  chb[b*256+op][0:1024]
__global__ void k_cvt_chart(const float* __restrict__ chart, u16* __restrict__ chb) {
  int i = blockIdx.x * blockDim.x + threadIdx.x;   // 2,097,152 threads
  int row = i >> 8;                 // b*256 + op, < 8192
  int k4 = (i & 255) * 4;
  int b = row >> 8, op = row & 255;
  const float4 v = *(const float4*)(chart + (size_t)(b * CHART_ROWS + op) * 2048 + 1024 + k4);
  u16x4 o = {f2bf(v.x), f2bf(v.y), f2bf(v.z), f2bf(v.w)};
  *(u16x4*)(chb + (size_t)row * 1024 + k4) = o;
}

// ---- fused gather + GEMM (5 gates) + gate nonlinearities -> c,h (bf16) ----
// 320 threads = 5 waves; wave = gate q. Tile: BM=64 rows x BG=64 g-cols.
// Wave tile 64x64 via 4x4 mfma_f32_16x16x32_bf16, 64 acc VGPRs.
__global__ __launch_bounds__(320, 3) void k_gemm(
    const float* __restrict__ chart, const u16* __restrict__ chb,
    const int* __restrict__ ops, const u16* __restrict__ Ubf,
    const float* __restrict__ bias, u16* __restrict__ cws, u16* __restrict__ hws,
    int step_base)
{
  __shared__ u16 As[BM * BK];        // 4 KB  bf16, row m: 4 chunks of 8, chunk c holds src chunk c^((m>>1)&3)
  __shared__ u16 Bs[5 * BG * BK];    // 20 KB bf16, row (q*64+g): chunk c holds src chunk c^((g>>1)&3)
  __shared__ float Ps[5 * 16 * 64];  // 20 KB preact exchange

  const int tid = threadIdx.x;
  const int wave = tid >> 6;         // 0..4 = gate q
  const int lane = tid & 63;
  const int lane15 = lane & 15, quad = lane >> 4;
  const int gblk = blockIdx.x;       // 0..15 (g block of 64)
  const int rb = blockIdx.y * BM;    // chunk-row base, 0..8128

  // A staging (threads 0..255): row mA = tid>>2, 16B chunk cA = tid&3
  const u16 *aL, *aR;
  int aSrcOff;
  {
    int mA = (tid & 255) >> 2, cA = tid & 3;
    int r = rb + mA;
    long flat = ((long)step_base * 1024 + r) * 2;
    int opL = ops[flat], opR = ops[flat + 1];
    int bb = (r >> 5) & 31;
    aL = chb + (size_t)(bb * 256 + opL) * 1024;
    aR = chb + (size_t)(bb * 256 + opR) * 1024;
    aSrcOff = (cA ^ ((mA >> 1) & 3)) * 8;
  }
  u16* aDst = &As[((tid & 255) >> 2) * 32 + (tid & 3) * 8];

  // B staging: 4 rounds x 320 lanes x 16B = 20 KB
  const u16* bSrc[4];
  u16* bDst[4];
#pragma unroll
  for (int t = 0; t < 4; ++t) {
    int rowB = t * 80 + (tid >> 2);
    int cB = tid & 3;
    int q_ = rowB >> 6, g = rowB & 63;
    bSrc[t] = Ubf + (size_t)(q_ * 1024 + gblk * 64 + g) * 2048 + (cB ^ ((g >> 1) & 3)) * 8;
    bDst[t] = &Bs[rowB * 32 + cB * 8];
  }

  // fragment LDS offsets (u16 elements)
  int aOff[4], bOff[4];
#pragma unroll
  for (int mt = 0; mt < 4; ++mt) {
    int m = mt * 16 + lane15;
    aOff[mt] = m * 32 + (quad ^ ((m >> 1) & 3)) * 8;
  }
#pragma unroll
  for (int gt = 0; gt < 4; ++gt) {
    int g = gt * 16 + lane15;
    bOff[gt] = (wave * 64 + g) * 32 + (quad ^ ((g >> 1) & 3)) * 8;
  }

  const f32x4 zero4 = {0.f, 0.f, 0.f, 0.f};
  f32x4 acc[4][4];
#pragma unroll
  for (int mt = 0; mt < 4; ++mt)
#pragma unroll
    for (int gt = 0; gt < 4; ++gt) acc[mt][gt] = zero4;

  for (int ko = 0; ko < 2048; ko += BK) {
    __syncthreads();
    if (wave < 4) {                       // stage A (4 KB)
      const u16* s = ((ko & 1024) ? aR : aL) + (ko & 1023) + aSrcOff;
      async16(s, aDst);
    }
#pragma unroll
    for (int t = 0; t < 4; ++t) async16(bSrc[t] + ko, bDst[t]);   // stage B (20 KB)
    __syncthreads();
    short8 af[4], bfr[4];
#pragma unroll
    for (int mt = 0; mt < 4; ++mt) af[mt] = *(const short8*)(As + aOff[mt]);
#pragma unroll
    for (int gt = 0; gt < 4; ++gt) bfr[gt] = *(const short8*)(Bs + bOff[gt]);
#pragma unroll
    for (int mt = 0; mt < 4; ++mt)
#pragma unroll
      for (int gt = 0; gt < 4; ++gt)
        acc[mt][gt] = __builtin_amdgcn_mfma_f32_16x16x32_bf16(af[mt], bfr[gt], acc[mt][gt], 0, 0, 0);
  }

  // epilogue: 4 stages of 16 rows; exchange 5 gate preacts via LDS
#pragma unroll
  for (int st = 0; st < 4; ++st) {
    __syncthreads();
#pragma unroll
    for (int gt = 0; gt < 4; ++gt)
#pragma unroll
      for (int rg = 0; rg < 4; ++rg) {
        int r16 = quad * 4 + rg;                    // C/D layout: row=quad*4+reg, col=lane15
        Ps[(wave * 16 + r16) * 64 + gt * 16 + lane15] = acc[st][gt][rg];
      }
    __syncthreads();
    if (tid < 256) {
#pragma unroll
      for (int half = 0; half < 4; ++half) {
        int idx = half * 256 + tid;
        int r16 = idx >> 6, gl = idx & 63;
        int r = rb + st * 16 + r16;
        int G = gblk * 64 + gl;
        long flat = ((long)step_base * 1024 + r) * 2;
        int opL = ops[flat], opR = ops[flat + 1];
        int bb = (r >> 5) & 31;
        float ccL = chart[(size_t)(bb * CHART_ROWS + opL) * 2048 + G];
        float ccR = chart[(size_t)(bb * CHART_ROWS + opR) * 2048 + G];
        float pi  = Ps[(0 * 16 + r16) * 64 + gl] + bias[G];
        float pfL = Ps[(1 * 16 + r16) * 64 + gl] + bias[1024 + G];
        float pfR = Ps[(2 * 16 + r16) * 64 + gl] + bias[2048 + G];
        float po  = Ps[(3 * 16 + r16) * 64 + gl] + bias[3072 + G];
        float pu  = Ps[(4 * 16 + r16) * 64 + gl] + bias[4096 + G];
        float cv = fast_sigmoid(pfL) * ccL + fast_sigmoid(pfR) * ccR + fast_sigmoid(pi) * fast_tanh(pu);
        float hv = fast_sigmoid(po) * fast_tanh(cv);
        cws[(size_t)r * 1024 + G] = f2bf(cv);
        hws[(size_t)r * 1024 + G] = f2bf(hv);
      }
    }
  }
}

// ---- per (step,b): energy + softmax over AMB=32 + weighted combine ----
__global__ __launch_bounds__(256) void k_combine(
    const u16* __restrict__ cws, const u16* __restrict__ hws,
    const float* __restrict__ eu, float* __restrict__ out, int step_base)
{
  __shared__ float us[1024];
  __shared__ float red[256];
  __shared__ float eL[32];
  const int tid = threadIdx.x;
  const int b = blockIdx.x;       // 0..31
  const int sc = blockIdx.y;      // 0..CH_STEPS-1

  float part = 0.f;
  for (int g = tid; g < 1024; g += 256) { float v = eu[g]; us[g] = v; part += v * v; }
  red[tid] = part;
  __syncthreads();
  for (int s = 128; s > 0; s >>= 1) { if (tid < s) red[tid] += red[tid + s]; __syncthreads(); }
  const float unorm = fmaxf(sqrtf(red[0]), 1e-8f);

  const int wave = tid >> 6, lane = tid & 63;
  const int rbase = (sc * 32 + b) * 32;
  for (int j = 0; j < 8; ++j) {
    int a = wave * 8 + j;
    const u16* hp = hws + (size_t)(rbase + a) * 1024;
    float dot = 0.f, nn = 0.f;
    for (int g = lane; g < 1024; g += 64) {
      float hv = bf2f(hp[g]);
      dot += hv * us[g];
      nn  += hv * hv;
    }
#pragma unroll
    for (int m = 1; m < 64; m <<= 1) { dot += __shfl_xor(dot, m, 64); nn += __shfl_xor(nn, m, 64); }
    if (lane == 0) eL[a] = dot / (unorm * fmaxf(sqrtf(nn), 1e-8f));
  }
  __syncthreads();

  float w[32];
  float mx = -1e30f;
#pragma unroll
  for (int a = 0; a < 32; ++a) mx = fmaxf(mx, eL[a]);
  float S = 0.f;
#pragma unroll
  for (int a = 0; a < 32; ++a) { w[a] = __expf(eL[a] - mx); S += w[a]; }
  const float inv = 1.0f / S;

  float* orow = out + ((size_t)b * CHART_ROWS + 256 + step_base + sc) * 2048;
  for (int g = tid; g < 1024; g += 256) {
    float sc_ = 0.f, sh_ = 0.f;
#pragma unroll
    for (int a = 0; a < 32; ++a) {
      size_t off = (size_t)(rbase + a) * 1024 + g;
      sc_ += w[a] * bf2f(cws[off]);
      sh_ += w[a] * bf2f(hws[off]);
    }
    orow[g] = sc_ * inv;
    orow[1024 + g] = sh_ * inv;
  }
}

extern "C" void kernel_launch(void* const* d_in, const int* in_sizes, int n_in,
                              void* d_out, int out_size, void* d_ws, size_t ws_size,
                              hipStream_t stream) {
  (void)in_sizes; (void)n_in; (void)out_size; (void)ws_size;
  const float* chart = (const float*)d_in[0];
  const int*   ops   = (const int*)d_in[1];
  // d_in[2] = start_index (256, hard-coded)
  const float* U     = (const float*)d_in[3];
  const float* bias  = (const float*)d_in[4];
  const float* eu    = (const float*)d_in[5];
  float* out = (float*)d_out;
  char* ws = (char*)d_ws;

  u16* Ubf = (u16*)ws;                                  // 20,971,520 B
  u16* chb = (u16*)(ws + 20971520);                     // 16,777,216 B
  u16* cws = (u16*)(ws + 20971520 + 16777216);          // 16,777,216 B
  u16* hws = (u16*)(ws + 20971520 + 2 * 16777216);      // 16,777,216 B  (total 68 MB)

  // rows < 256 of output = input copy (rows >= 256 get overwritten below)
  hipMemcpyAsync(out, chart, (size_t)32 * CHART_ROWS * 2048 * 4, hipMemcpyDeviceToDevice, stream);
  k_cvt_u<<<10240, 256, 0, stream>>>((const float4*)U, Ubf);
  k_cvt_chart<<<8192, 256, 0, stream>>>(chart, chb);

  for (int cb = 0; cb < 128; cb += CH_STEPS) {
    k_gemm<<<dim3(16, RCHUNK / BM), 320, 0, stream>>>(chart, chb, ops, Ubf, bias, cws, hws, cb);
    k_combine<<<dim3(32, CH_STEPS), 256, 0, stream>>>(cws, hws, eu, out, cb);
  }
}

// Round 2
// 1646.916 us; speedup vs baseline: 4.0121x; 4.0121x over previous
//
#include <hip/hip_runtime.h>

// SequentialChart: ops < START(256) => steps independent. Key algebraic cut:
// preact rows are gathers over only 8192 distinct (b,op) sources, so
// precompute PL[b,op]=U_left@h(b,op), PR[b,op]=U_right@h(b,op) (0.172 TFLOP,
// 16x less than projecting all 131072 gathered rows), then gates = gather-add.

typedef unsigned int u32;
typedef unsigned short u16;
typedef __attribute__((ext_vector_type(8))) short short8;
typedef __attribute__((ext_vector_type(4))) float f32x4;
typedef __attribute__((ext_vector_type(4))) u16 u16x4;
typedef __attribute__((ext_vector_type(8))) u16 u16x8;
typedef _Float16 h8 __attribute__((ext_vector_type(8)));

#define CHART_ROWS 384

__device__ __forceinline__ u16 f2bf(float f) {           // fp32 -> bf16 RNE
  u32 u = __float_as_uint(f);
  u32 r = u + 0x7fffu + ((u >> 16) & 1u);
  return (u16)(r >> 16);
}
__device__ __forceinline__ float bf2f(u16 v) { return __uint_as_float(((u32)v) << 16); }
__device__ __forceinline__ float fast_sigmoid(float x) { return __builtin_amdgcn_rcpf(1.0f + __expf(-x)); }
__device__ __forceinline__ float fast_tanh(float x)    { return 1.0f - 2.0f * __builtin_amdgcn_rcpf(1.0f + __expf(2.0f * x)); }

__device__ __forceinline__ void async16(const void* g, void* l) {
  __builtin_amdgcn_global_load_lds((const __attribute__((address_space(1))) u32*)g,
                                   (__attribute__((address_space(3))) u32*)l, 16, 0, 0);
}

// ---- U (5120x2048 fp32) -> bf16, same row-major layout
__global__ void k_cvt_u(const float4* __restrict__ U4, u16* __restrict__ Ubf) {
  int i = blockIdx.x * blockDim.x + threadIdx.x;   // 2,621,440 threads
  float4 v = U4[i];
  u16x4 o = {f2bf(v.x), f2bf(v.y), f2bf(v.z), f2bf(v.w)};
  *(u16x4*)(Ubf + (size_t)i * 4) = o;
}

// ---- chart[b][op<256][1024:2048] -> bf16  chb[b*256+op][0:1024]
__global__ void k_cvt_chart(const float* __restrict__ chart, u16* __restrict__ chb) {
  int i = blockIdx.x * blockDim.x + threadIdx.x;   // 2,097,152 threads
  int row = i >> 8;                 // b*256 + op, < 8192
  int k4 = (i & 255) * 4;
  int b = row >> 8, op = row & 255;
  const float4 v = *(const float4*)(chart + (size_t)(b * CHART_ROWS + op) * 2048 + 1024 + k4);
  u16x4 o = {f2bf(v.x), f2bf(v.y), f2bf(v.z), f2bf(v.w)};
  *(u16x4*)(chb + (size_t)row * 1024 + k4) = o;
}

// ---- P[half][bo][G] = sum_k chb[bg*2048+bo][k] * U[G][half*1024+k] ----
// m97-style: 128x128 tile, 4 waves, wave=64x64 quadrant, BK=32, K=1024.
// A rows are CONTIGUOUS chb rows (the gather moved to k_gates).
__global__ __launch_bounds__(256, 3) void k_gemm_p(
    const u16* __restrict__ chb, const u16* __restrict__ Ubf,
    _Float16* __restrict__ P, int bg)
{
  __shared__ u16 As[128 * 32];   // 8 KB
  __shared__ u16 Bs[128 * 32];   // 8 KB
  const int tid = threadIdx.x;
  const int wave = tid >> 6, lane = tid & 63;
  const int lane15 = lane & 15, quad = lane >> 4;
  const int bx = blockIdx.x;        // G tile (0..39)
  const int by = blockIdx.y;        // 0..31
  const int half = by >> 4;
  const int rt = by & 15;           // row tile within half

  const u16* aSrc[2]; const u16* bSrc[2];
  u16* aDst[2]; u16* bDst[2];
#pragma unroll
  for (int rnd = 0; rnd < 2; ++rnd) {
    int idx = rnd * 256 + tid;
    int row = idx >> 2, c = idx & 3;      // chunk c at position c, src chunk c^((row>>1)&3)
    aSrc[rnd] = chb + (size_t)(bg * 2048 + rt * 128 + row) * 1024 + (c ^ ((row >> 1) & 3)) * 8;
    aDst[rnd] = As + (size_t)idx * 8;
    bSrc[rnd] = Ubf + (size_t)(bx * 128 + row) * 2048 + half * 1024 + (c ^ ((row >> 1) & 3)) * 8;
    bDst[rnd] = Bs + (size_t)idx * 8;
  }

  int aOff[4], bOff[4];
#pragma unroll
  for (int mt = 0; mt < 4; ++mt) {
    int m = (wave & 1) * 64 + mt * 16 + lane15;
    aOff[mt] = m * 32 + (quad ^ ((m >> 1) & 3)) * 8;
  }
#pragma unroll
  for (int gt = 0; gt < 4; ++gt) {
    int g = (wave >> 1) * 64 + gt * 16 + lane15;
    bOff[gt] = g * 32 + (quad ^ ((g >> 1) & 3)) * 8;
  }

  const f32x4 zero4 = {0.f, 0.f, 0.f, 0.f};
  f32x4 acc[4][4];
#pragma unroll
  for (int mt = 0; mt < 4; ++mt)
#pragma unroll
    for (int gt = 0; gt < 4; ++gt) acc[mt][gt] = zero4;

  for (int ko = 0; ko < 1024; ko += 32) {
    __syncthreads();
#pragma unroll
    for (int rnd = 0; rnd < 2; ++rnd) {
      async16(aSrc[rnd] + ko, aDst[rnd]);
      async16(bSrc[rnd] + ko, bDst[rnd]);
    }
    __syncthreads();
    short8 af[4], bfr[4];
#pragma unroll
    for (int mt = 0; mt < 4; ++mt) af[mt] = *(const short8*)(As + aOff[mt]);
#pragma unroll
    for (int gt = 0; gt < 4; ++gt) bfr[gt] = *(const short8*)(Bs + bOff[gt]);
#pragma unroll
    for (int mt = 0; mt < 4; ++mt)
#pragma unroll
      for (int gt = 0; gt < 4; ++gt)
        acc[mt][gt] = __builtin_amdgcn_mfma_f32_16x16x32_bf16(af[mt], bfr[gt], acc[mt][gt], 0, 0, 0);
  }

  // epilogue: C/D layout row=quad*4+reg (A row), col=lane15 (B row)
#pragma unroll
  for (int mt = 0; mt < 4; ++mt)
#pragma unroll
    for (int rg = 0; rg < 4; ++rg) {
      int row = (wave & 1) * 64 + mt * 16 + quad * 4 + rg;
      size_t pbase = (size_t)(half * 2048 + rt * 128 + row) * 5120 + bx * 128 + (wave >> 1) * 64;
#pragma unroll
      for (int gt = 0; gt < 4; ++gt)
        P[pbase + gt * 16 + lane15] = (_Float16)acc[mt][gt][rg];
    }
}

// ---- gather-add + gates: preact = PL[b,opL] + PR[b,opR] + bias -> c,h bf16
// wave = one row; grid (256, 8 b_local) so blocks cluster by b for L2 locality.
__global__ __launch_bounds__(256) void k_gates(
    const float* __restrict__ chart, const _Float16* __restrict__ P,
    const int* __restrict__ ops, const float* __restrict__ bias,
    u16* __restrict__ cws, u16* __restrict__ hws, int bg, int sc)
{
  const int wave = threadIdx.x >> 6, lane = threadIdx.x & 63;
  const int b_local = blockIdx.y;
  const int rr = blockIdx.x * 4 + wave;       // 0..1023 rows for this b in chunk
  const int s_local = rr >> 5, a = rr & 31;
  const int step = sc * 32 + s_local;
  const int b = bg * 8 + b_local;
  const long opflat = (((long)step * 32 + b) * 32 + a) * 2;
  const int opL = ops[opflat], opR = ops[opflat + 1];
  const _Float16* PL = P + (size_t)(b_local * 256 + opL) * 5120;
  const _Float16* PR = P + (size_t)(2048 + b_local * 256 + opR) * 5120;
  const float* ccLr = chart + (size_t)(b * CHART_ROWS + opL) * 2048;
  const float* ccRr = chart + (size_t)(b * CHART_ROWS + opR) * 2048;
  const int rch = s_local * 256 + b_local * 32 + a;
  u16* crow = cws + (size_t)rch * 1024;
  u16* hrow = hws + (size_t)rch * 1024;

#pragma unroll
  for (int jc = 0; jc < 2; ++jc) {
    const int j0 = jc * 512 + lane * 8;       // 8 consecutive j per lane, coalesced
    h8 pl[5], pr[5];
    float bia[5][8];
#pragma unroll
    for (int q = 0; q < 5; ++q) {
      pl[q] = *(const h8*)(PL + q * 1024 + j0);
      pr[q] = *(const h8*)(PR + q * 1024 + j0);
      float4 b0 = *(const float4*)(bias + q * 1024 + j0);
      float4 b1 = *(const float4*)(bias + q * 1024 + j0 + 4);
      bia[q][0] = b0.x; bia[q][1] = b0.y; bia[q][2] = b0.z; bia[q][3] = b0.w;
      bia[q][4] = b1.x; bia[q][5] = b1.y; bia[q][6] = b1.z; bia[q][7] = b1.w;
    }
    float4 cl0 = *(const float4*)(ccLr + j0), cl1 = *(const float4*)(ccLr + j0 + 4);
    float4 cr0 = *(const float4*)(ccRr + j0), cr1 = *(const float4*)(ccRr + j0 + 4);
    float ccl[8] = {cl0.x, cl0.y, cl0.z, cl0.w, cl1.x, cl1.y, cl1.z, cl1.w};
    float ccr[8] = {cr0.x, cr0.y, cr0.z, cr0.w, cr1.x, cr1.y, cr1.z, cr1.w};
    u16x8 co, ho;
#pragma unroll
    for (int j = 0; j < 8; ++j) {
      float pi  = (float)pl[0][j] + (float)pr[0][j] + bia[0][j];
      float pfL = (float)pl[1][j] + (float)pr[1][j] + bia[1][j];
      float pfR = (float)pl[2][j] + (float)pr[2][j] + bia[2][j];
      float po  = (float)pl[3][j] + (float)pr[3][j] + bia[3][j];
      float pu  = (float)pl[4][j] + (float)pr[4][j] + bia[4][j];
      float cv = fast_sigmoid(pfL) * ccl[j] + fast_sigmoid(pfR) * ccr[j]
               + fast_sigmoid(pi) * fast_tanh(pu);
      float hv = fast_sigmoid(po) * fast_tanh(cv);
      co[j] = f2bf(cv);
      ho[j] = f2bf(hv);
    }
    *(u16x8*)(crow + j0) = co;
    *(u16x8*)(hrow + j0) = ho;
  }
}

// ---- per (step,b): energy + softmax over AMB=32 + weighted combine ----
__global__ __launch_bounds__(256) void k_combine(
    const u16* __restrict__ cws, const u16* __restrict__ hws,
    const float* __restrict__ eu, float* __restrict__ out, int bg, int sc)
{
  __shared__ float us[1024];
  __shared__ float red[256];
  __shared__ float eL[32];
  const int tid = threadIdx.x;
  const int b_local = blockIdx.x;   // 0..7
  const int s_local = blockIdx.y;   // 0..31

  float part = 0.f;
  for (int g = tid; g < 1024; g += 256) { float v = eu[g]; us[g] = v; part += v * v; }
  red[tid] = part;
  __syncthreads();
  for (int s = 128; s > 0; s >>= 1) { if (tid < s) red[tid] += red[tid + s]; __syncthreads(); }
  const float unorm = fmaxf(sqrtf(red[0]), 1e-8f);

  const int wave = tid >> 6, lane = tid & 63;
  const int rbase = s_local * 256 + b_local * 32;
  for (int j = 0; j < 8; ++j) {
    int a = wave * 8 + j;
    const u16* hp = hws + (size_t)(rbase + a) * 1024;
    float dot = 0.f, nn = 0.f;
    for (int g = lane; g < 1024; g += 64) {
      float hv = bf2f(hp[g]);
      dot += hv * us[g];
      nn  += hv * hv;
    }
#pragma unroll
    for (int m = 1; m < 64; m <<= 1) { dot += __shfl_xor(dot, m, 64); nn += __shfl_xor(nn, m, 64); }
    if (lane == 0) eL[a] = dot / (unorm * fmaxf(sqrtf(nn), 1e-8f));
  }
  __syncthreads();

  float w[32];
  float mx = -1e30f;
#pragma unroll
  for (int a = 0; a < 32; ++a) mx = fmaxf(mx, eL[a]);
  float S = 0.f;
#pragma unroll
  for (int a = 0; a < 32; ++a) { w[a] = __expf(eL[a] - mx); S += w[a]; }
  const float inv = 1.0f / S;

  const int b = bg * 8 + b_local;
  const int step = sc * 32 + s_local;
  float* orow = out + ((size_t)b * CHART_ROWS + 256 + step) * 2048;
  for (int g = tid; g < 1024; g += 256) {
    float sc_ = 0.f, sh_ = 0.f;
#pragma unroll
    for (int a = 0; a < 32; ++a) {
      size_t off = (size_t)(rbase + a) * 1024 + g;
      sc_ += w[a] * bf2f(cws[off]);
      sh_ += w[a] * bf2f(hws[off]);
    }
    orow[g] = sc_ * inv;
    orow[1024 + g] = sh_ * inv;
  }
}

extern "C" void kernel_launch(void* const* d_in, const int* in_sizes, int n_in,
                              void* d_out, int out_size, void* d_ws, size_t ws_size,
                              hipStream_t stream) {
  (void)in_sizes; (void)n_in; (void)out_size; (void)ws_size;
  const float* chart = (const float*)d_in[0];
  const int*   ops   = (const int*)d_in[1];
  // d_in[2] = start_index (256, hard-coded)
  const float* U     = (const float*)d_in[3];
  const float* bias  = (const float*)d_in[4];
  const float* eu    = (const float*)d_in[5];
  float* out = (float*)d_out;
  char* ws = (char*)d_ws;

  u16*      Ubf = (u16*)ws;                       // 20,971,520 B
  u16*      chb = (u16*)(ws + 20971520);          // 16,777,216 B
  _Float16* P   = (_Float16*)(ws + 37748736);     // 41,943,040 B (2 halves x 2048 x 5120 fp16)
  u16*      cws = (u16*)(ws + 79691776);          // 16,777,216 B (32 steps x 8 b x 32 a x 1024)
  u16*      hws = (u16*)(ws + 96468992);          // 16,777,216 B  -> total 113,246,208 B

  hipMemcpyAsync(out, chart, (size_t)32 * CHART_ROWS * 2048 * 4, hipMemcpyDeviceToDevice, stream);
  k_cvt_u<<<10240, 256, 0, stream>>>((const float4*)U, Ubf);
  k_cvt_chart<<<8192, 256, 0, stream>>>(chart, chb);

  for (int bg = 0; bg < 4; ++bg) {                  // 8 batches per group
    k_gemm_p<<<dim3(40, 32), 256, 0, stream>>>(chb, Ubf, P, bg);
    for (int sc = 0; sc < 4; ++sc) {                // 32 steps per chunk
      k_gates<<<dim3(256, 8), 256, 0, stream>>>(chart, P, ops, bias, cws, hws, bg, sc);
      k_combine<<<dim3(8, 32), 256, 0, stream>>>(cws, hws, eu, out, bg, sc);
    }
  }
}

// Round 3
// 913.526 us; speedup vs baseline: 7.2331x; 1.8028x over previous
//
#include <hip/hip_runtime.h>

// SequentialChart: ops < START(256) => steps independent. Algebraic cut:
// PL[b,op]=U_left@h(b,op), PR[b,op]=U_right@h(b,op) (16x fewer FLOPs than the
// naive gathered GEMM), then preact = PL[opL]+PR[opR]+bias (gather-add).
// This round: fuse gates+softmax-combine into one kernel (block=(step,b),
// h/c staged in 131KB LDS) to kill the cws/hws HBM round-trip.

typedef unsigned int u32;
typedef unsigned short u16;
typedef __attribute__((ext_vector_type(8))) short short8;
typedef __attribute__((ext_vector_type(4))) float f32x4;
typedef __attribute__((ext_vector_type(4))) u16 u16x4;
typedef __attribute__((ext_vector_type(8))) u16 u16x8;
typedef _Float16 h8 __attribute__((ext_vector_type(8)));

#define CHART_ROWS 384

__device__ __forceinline__ u16 f2bf(float f) {           // fp32 -> bf16 RNE
  u32 u = __float_as_uint(f);
  u32 r = u + 0x7fffu + ((u >> 16) & 1u);
  return (u16)(r >> 16);
}
__device__ __forceinline__ float bf2f(u16 v) { return __uint_as_float(((u32)v) << 16); }
__device__ __forceinline__ float fast_sigmoid(float x) { return __builtin_amdgcn_rcpf(1.0f + __expf(-x)); }
__device__ __forceinline__ float fast_tanh(float x)    { return 1.0f - 2.0f * __builtin_amdgcn_rcpf(1.0f + __expf(2.0f * x)); }

__device__ __forceinline__ void async16(const void* g, void* l) {
  __builtin_amdgcn_global_load_lds((const __attribute__((address_space(1))) u32*)g,
                                   (__attribute__((address_space(3))) u32*)l, 16, 0, 0);
}

// ---- U (5120x2048 fp32) -> bf16, same row-major layout
__global__ void k_cvt_u(const float4* __restrict__ U4, u16* __restrict__ Ubf) {
  int i = blockIdx.x * blockDim.x + threadIdx.x;   // 2,621,440 threads
  float4 v = U4[i];
  u16x4 o = {f2bf(v.x), f2bf(v.y), f2bf(v.z), f2bf(v.w)};
  *(u16x4*)(Ubf + (size_t)i * 4) = o;
}

// ---- chart rows<256: h-half (cols 1024:2048) -> chb, c-half (0:1024) -> chc
__global__ void k_cvt_chart(const float* __restrict__ chart,
                            u16* __restrict__ chb, u16* __restrict__ chc) {
  int i = blockIdx.x * blockDim.x + threadIdx.x;   // 2,097,152 threads
  int row = i >> 8;                 // b*256 + op, < 8192
  int k4 = (i & 255) * 4;
  int b = row >> 8, op = row & 255;
  const float* src = chart + (size_t)(b * CHART_ROWS + op) * 2048;
  const float4 vh = *(const float4*)(src + 1024 + k4);
  const float4 vc = *(const float4*)(src + k4);
  u16x4 oh = {f2bf(vh.x), f2bf(vh.y), f2bf(vh.z), f2bf(vh.w)};
  u16x4 oc = {f2bf(vc.x), f2bf(vc.y), f2bf(vc.z), f2bf(vc.w)};
  *(u16x4*)(chb + (size_t)row * 1024 + k4) = oh;
  *(u16x4*)(chc + (size_t)row * 1024 + k4) = oc;
}

// ---- P[half][bo][G] = sum_k chb[bg*2048+bo][k] * U[G][half*1024+k] ----
// m97-style: 128x128 tile, 4 waves, wave=64x64 quadrant, BK=32, K=1024.
__global__ __launch_bounds__(256, 3) void k_gemm_p(
    const u16* __restrict__ chb, const u16* __restrict__ Ubf,
    _Float16* __restrict__ P, int bg)
{
  __shared__ u16 As[128 * 32];   // 8 KB
  __shared__ u16 Bs[128 * 32];   // 8 KB
  const int tid = threadIdx.x;
  const int wave = tid >> 6, lane = tid & 63;
  const int lane15 = lane & 15, quad = lane >> 4;
  const int bx = blockIdx.x;        // G tile (0..39)
  const int by = blockIdx.y;        // 0..31
  const int half = by >> 4;
  const int rt = by & 15;           // row tile within half

  const u16* aSrc[2]; const u16* bSrc[2];
  u16* aDst[2]; u16* bDst[2];
#pragma unroll
  for (int rnd = 0; rnd < 2; ++rnd) {
    int idx = rnd * 256 + tid;
    int row = idx >> 2, c = idx & 3;
    aSrc[rnd] = chb + (size_t)(bg * 2048 + rt * 128 + row) * 1024 + (c ^ ((row >> 1) & 3)) * 8;
    aDst[rnd] = As + (size_t)idx * 8;
    bSrc[rnd] = Ubf + (size_t)(bx * 128 + row) * 2048 + half * 1024 + (c ^ ((row >> 1) & 3)) * 8;
    bDst[rnd] = Bs + (size_t)idx * 8;
  }

  int aOff[4], bOff[4];
#pragma unroll
  for (int mt = 0; mt < 4; ++mt) {
    int m = (wave & 1) * 64 + mt * 16 + lane15;
    aOff[mt] = m * 32 + (quad ^ ((m >> 1) & 3)) * 8;
  }
#pragma unroll
  for (int gt = 0; gt < 4; ++gt) {
    int g = (wave >> 1) * 64 + gt * 16 + lane15;
    bOff[gt] = g * 32 + (quad ^ ((g >> 1) & 3)) * 8;
  }

  const f32x4 zero4 = {0.f, 0.f, 0.f, 0.f};
  f32x4 acc[4][4];
#pragma unroll
  for (int mt = 0; mt < 4; ++mt)
#pragma unroll
    for (int gt = 0; gt < 4; ++gt) acc[mt][gt] = zero4;

  for (int ko = 0; ko < 1024; ko += 32) {
    __syncthreads();
#pragma unroll
    for (int rnd = 0; rnd < 2; ++rnd) {
      async16(aSrc[rnd] + ko, aDst[rnd]);
      async16(bSrc[rnd] + ko, bDst[rnd]);
    }
    __syncthreads();
    short8 af[4], bfr[4];
#pragma unroll
    for (int mt = 0; mt < 4; ++mt) af[mt] = *(const short8*)(As + aOff[mt]);
#pragma unroll
    for (int gt = 0; gt < 4; ++gt) bfr[gt] = *(const short8*)(Bs + bOff[gt]);
#pragma unroll
    for (int mt = 0; mt < 4; ++mt)
#pragma unroll
      for (int gt = 0; gt < 4; ++gt)
        acc[mt][gt] = __builtin_amdgcn_mfma_f32_16x16x32_bf16(af[mt], bfr[gt], acc[mt][gt], 0, 0, 0);
  }

#pragma unroll
  for (int mt = 0; mt < 4; ++mt)
#pragma unroll
    for (int rg = 0; rg < 4; ++rg) {
      int row = (wave & 1) * 64 + mt * 16 + quad * 4 + rg;
      size_t pbase = (size_t)(half * 2048 + rt * 128 + row) * 5120 + bx * 128 + (wave >> 1) * 64;
#pragma unroll
      for (int gt = 0; gt < 4; ++gt)
        P[pbase + gt * 16 + lane15] = (_Float16)acc[mt][gt][rg];
    }
}

// ---- fused: gather-add preact + gates + energy + softmax + combine ----
// Block = (step, b_local), 512 thr = 8 waves; wave w does rows a = t*8+w.
// h,c (bf16) staged in LDS (lane-permuted: conflict-free b128 writes, 2-way
// u32 column reads). Writes one 2048-float output row.
__global__ __launch_bounds__(512, 1) void k_fused(
    const u16* __restrict__ chc, const _Float16* __restrict__ P,
    const int* __restrict__ ops, const float* __restrict__ bias,
    const float* __restrict__ eu, float* __restrict__ out, int bg)
{
  __shared__ u16 hS[32 * 1024];   // 64 KB
  __shared__ u16 cS[32 * 1024];   // 64 KB
  __shared__ float eS[32];

  const int tid = threadIdx.x;
  const int wave = tid >> 6, lane = tid & 63;
  const int step = blockIdx.x;
  const int b_local = blockIdx.y;
  const int b = bg * 8 + b_local;

  // per-lane slice of u (16 cols) + unorm (each wave covers all 1024 cols)
  float ureg[16];
  *(float4*)&ureg[0]  = *(const float4*)(eu + lane * 16);
  *(float4*)&ureg[4]  = *(const float4*)(eu + lane * 16 + 4);
  *(float4*)&ureg[8]  = *(const float4*)(eu + lane * 16 + 8);
  *(float4*)&ureg[12] = *(const float4*)(eu + lane * 16 + 12);
  float part = 0.f;
#pragma unroll
  for (int j = 0; j < 16; ++j) part += ureg[j] * ureg[j];
#pragma unroll
  for (int m = 1; m < 64; m <<= 1) part += __shfl_xor(part, m, 64);
  const float unorm = fmaxf(sqrtf(part), 1e-8f);

  // per-lane bias slice (5 gates x 16 cols)
  float bia[5][16];
#pragma unroll
  for (int q = 0; q < 5; ++q) {
    *(float4*)&bia[q][0]  = *(const float4*)(bias + q * 1024 + lane * 16);
    *(float4*)&bia[q][4]  = *(const float4*)(bias + q * 1024 + lane * 16 + 4);
    *(float4*)&bia[q][8]  = *(const float4*)(bias + q * 1024 + lane * 16 + 8);
    *(float4*)&bia[q][12] = *(const float4*)(bias + q * 1024 + lane * 16 + 12);
  }

  for (int t = 0; t < 4; ++t) {
    const int a = t * 8 + wave;
    const long opflat = (((long)step * 32 + b) * 32 + a) * 2;
    const int opL = ops[opflat], opR = ops[opflat + 1];
    const _Float16* PLp = P + (size_t)(b_local * 256 + opL) * 5120;
    const _Float16* PRp = P + (size_t)(2048 + b_local * 256 + opR) * 5120;
    const u16* ccLr = chc + (size_t)(b * 256 + opL) * 1024;
    const u16* ccRr = chc + (size_t)(b * 256 + opR) * 1024;
    float dot = 0.f, nn = 0.f;
#pragma unroll
    for (int sub = 0; sub < 2; ++sub) {
      const int g8 = lane * 16 + sub * 8;
      h8 pl[5], pr[5];
#pragma unroll
      for (int q = 0; q < 5; ++q) {
        pl[q] = *(const h8*)(PLp + q * 1024 + g8);
        pr[q] = *(const h8*)(PRp + q * 1024 + g8);
      }
      const u16x8 cl = *(const u16x8*)(ccLr + g8);
      const u16x8 cr = *(const u16x8*)(ccRr + g8);
      u16x8 co, ho;
#pragma unroll
      for (int j = 0; j < 8; ++j) {
        const int jj = sub * 8 + j;
        float pi  = (float)pl[0][j] + (float)pr[0][j] + bia[0][jj];
        float pfL = (float)pl[1][j] + (float)pr[1][j] + bia[1][jj];
        float pfR = (float)pl[2][j] + (float)pr[2][j] + bia[2][jj];
        float po  = (float)pl[3][j] + (float)pr[3][j] + bia[3][jj];
        float pu  = (float)pl[4][j] + (float)pr[4][j] + bia[4][jj];
        float cv = fast_sigmoid(pfL) * bf2f(cl[j]) + fast_sigmoid(pfR) * bf2f(cr[j])
                 + fast_sigmoid(pi) * fast_tanh(pu);
        float hv = fast_sigmoid(po) * fast_tanh(cv);
        co[j] = f2bf(cv);
        ho[j] = f2bf(hv);
        dot += hv * ureg[jj];
        nn  += hv * hv;
      }
      const int lofs = a * 1024 + sub * 512 + lane * 8;   // permuted layout
      *(u16x8*)(hS + lofs) = ho;
      *(u16x8*)(cS + lofs) = co;
    }
#pragma unroll
    for (int m = 1; m < 64; m <<= 1) {
      dot += __shfl_xor(dot, m, 64);
      nn  += __shfl_xor(nn, m, 64);
    }
    if (lane == 0) eS[a] = dot / (unorm * fmaxf(sqrtf(nn), 1e-8f));
  }
  __syncthreads();

  // softmax weights (all threads, from LDS broadcast reads)
  float w[32];
  float mx = -1e30f;
#pragma unroll
  for (int a = 0; a < 32; ++a) mx = fmaxf(mx, eS[a]);
  float S = 0.f;
#pragma unroll
  for (int a = 0; a < 32; ++a) { w[a] = __expf(eS[a] - mx); S += w[a]; }
  const float inv = 1.0f / S;

  // combine: thread owns cols g0, g0+1 (u32 per LDS row; permuted index)
  const int g0 = tid * 2;
  const int p = ((g0 >> 3) & 1) * 512 + (g0 >> 4) * 8 + (g0 & 7);
  float sc0 = 0.f, sc1 = 0.f, sh0 = 0.f, sh1 = 0.f;
#pragma unroll
  for (int a = 0; a < 32; ++a) {
    const u32 hv = *(const u32*)(hS + a * 1024 + p);
    const u32 cv = *(const u32*)(cS + a * 1024 + p);
    sc0 += w[a] * __uint_as_float(cv << 16);
    sc1 += w[a] * __uint_as_float(cv & 0xffff0000u);
    sh0 += w[a] * __uint_as_float(hv << 16);
    sh1 += w[a] * __uint_as_float(hv & 0xffff0000u);
  }
  float* orow = out + ((size_t)b * CHART_ROWS + 256 + step) * 2048;
  *(float2*)(orow + g0)        = make_float2(sc0 * inv, sc1 * inv);
  *(float2*)(orow + 1024 + g0) = make_float2(sh0 * inv, sh1 * inv);
}

extern "C" void kernel_launch(void* const* d_in, const int* in_sizes, int n_in,
                              void* d_out, int out_size, void* d_ws, size_t ws_size,
                              hipStream_t stream) {
  (void)in_sizes; (void)n_in; (void)out_size; (void)ws_size;
  const float* chart = (const float*)d_in[0];
  const int*   ops   = (const int*)d_in[1];
  // d_in[2] = start_index (256, hard-coded)
  const float* U     = (const float*)d_in[3];
  const float* bias  = (const float*)d_in[4];
  const float* eu    = (const float*)d_in[5];
  float* out = (float*)d_out;
  char* ws = (char*)d_ws;

  u16*      Ubf = (u16*)ws;                       // 20,971,520 B
  u16*      chb = (u16*)(ws + 20971520);          // 16,777,216 B
  u16*      chc = (u16*)(ws + 37748736);          // 16,777,216 B
  _Float16* P   = (_Float16*)(ws + 54525952);     // 41,943,040 B -> total 96,468,992 B

  hipMemcpyAsync(out, chart, (size_t)32 * CHART_ROWS * 2048 * 4, hipMemcpyDeviceToDevice, stream);
  k_cvt_u<<<10240, 256, 0, stream>>>((const float4*)U, Ubf);
  k_cvt_chart<<<8192, 256, 0, stream>>>(chart, chb, chc);

  for (int bg = 0; bg < 4; ++bg) {                  // 8 batches per group
    k_gemm_p<<<dim3(40, 32), 256, 0, stream>>>(chb, Ubf, P, bg);
    k_fused<<<dim3(128, 8), 512, 0, stream>>>(chc, P, ops, bias, eu, out, bg);
  }
}

// Round 4
// 837.466 us; speedup vs baseline: 7.8900x; 1.0908x over previous
//
#include <hip/hip_runtime.h>

// SequentialChart: ops < START(256) => steps independent. Algebraic cut:
// PL[b,op]=U_left@h(b,op), PR[b,op]=U_right@h(b,op) (16x fewer FLOPs),
// preact = PL[opL]+PR[opR] (bias folded into PL at GEMM epilogue).
// Fused gates+softmax+combine: c in 64KB LDS, h in packed-bf16 regs,
// cross-wave h-reduction through reused LDS -> 2 blocks/CU.

typedef unsigned int u32;
typedef unsigned short u16;
typedef __attribute__((ext_vector_type(8))) short short8;
typedef __attribute__((ext_vector_type(4))) float f32x4;
typedef __attribute__((ext_vector_type(4))) u16 u16x4;
typedef __attribute__((ext_vector_type(8))) u16 u16x8;
typedef _Float16 h8 __attribute__((ext_vector_type(8)));

#define CHART_ROWS 384

__device__ __forceinline__ u16 f2bf(float f) {           // fp32 -> bf16 RNE
  u32 u = __float_as_uint(f);
  u32 r = u + 0x7fffu + ((u >> 16) & 1u);
  return (u16)(r >> 16);
}
__device__ __forceinline__ float bf2f(u16 v) { return __uint_as_float(((u32)v) << 16); }
__device__ __forceinline__ float fast_sigmoid(float x) { return __builtin_amdgcn_rcpf(1.0f + __expf(-x)); }
__device__ __forceinline__ float fast_tanh(float x)    { return 1.0f - 2.0f * __builtin_amdgcn_rcpf(1.0f + __expf(2.0f * x)); }

__device__ __forceinline__ void async16(const void* g, void* l) {
  __builtin_amdgcn_global_load_lds((const __attribute__((address_space(1))) u32*)g,
                                   (__attribute__((address_space(3))) u32*)l, 16, 0, 0);
}

// ---- U (5120x2048 fp32) -> bf16, same row-major layout
__global__ void k_cvt_u(const float4* __restrict__ U4, u16* __restrict__ Ubf) {
  int i = blockIdx.x * blockDim.x + threadIdx.x;   // 2,621,440 threads
  float4 v = U4[i];
  u16x4 o = {f2bf(v.x), f2bf(v.y), f2bf(v.z), f2bf(v.w)};
  *(u16x4*)(Ubf + (size_t)i * 4) = o;
}

// ---- chart rows<256: h-half -> chb, c-half -> chc; also copy rows<256 to out
__global__ void k_cvt_chart(const float* __restrict__ chart,
                            u16* __restrict__ chb, u16* __restrict__ chc,
                            float* __restrict__ out) {
  int i = blockIdx.x * blockDim.x + threadIdx.x;   // 2,097,152 threads
  int row = i >> 8;                 // b*256 + op, < 8192
  int k4 = (i & 255) * 4;
  int b = row >> 8, op = row & 255;
  const size_t base = (size_t)(b * CHART_ROWS + op) * 2048;
  const float4 vh = *(const float4*)(chart + base + 1024 + k4);
  const float4 vc = *(const float4*)(chart + base + k4);
  u16x4 oh = {f2bf(vh.x), f2bf(vh.y), f2bf(vh.z), f2bf(vh.w)};
  u16x4 oc = {f2bf(vc.x), f2bf(vc.y), f2bf(vc.z), f2bf(vc.w)};
  *(u16x4*)(chb + (size_t)row * 1024 + k4) = oh;
  *(u16x4*)(chc + (size_t)row * 1024 + k4) = oc;
  *(float4*)(out + base + k4) = vc;          // rows < 256 pass through
  *(float4*)(out + base + 1024 + k4) = vh;   // rows >= 256 written by k_fused
}

// ---- P[half][bo][G] = sum_k chb[bg*2048+bo][k] * U[G][half*1024+k] (+bias on half0)
__global__ __launch_bounds__(256, 4) void k_gemm_p(
    const u16* __restrict__ chb, const u16* __restrict__ Ubf,
    const float* __restrict__ bias, _Float16* __restrict__ P, int bg)
{
  __shared__ u16 As[128 * 32];   // 8 KB
  __shared__ u16 Bs[128 * 32];   // 8 KB
  const int tid = threadIdx.x;
  const int wave = tid >> 6, lane = tid & 63;
  const int lane15 = lane & 15, quad = lane >> 4;
  const int bx = blockIdx.x;        // G tile (0..39)
  const int by = blockIdx.y;        // 0..31
  const int half = by >> 4;
  const int rt = by & 15;           // row tile within half

  const u16* aSrc[2]; const u16* bSrc[2];
  u16* aDst[2]; u16* bDst[2];
#pragma unroll
  for (int rnd = 0; rnd < 2; ++rnd) {
    int idx = rnd * 256 + tid;
    int row = idx >> 2, c = idx & 3;
    aSrc[rnd] = chb + (size_t)(bg * 2048 + rt * 128 + row) * 1024 + (c ^ ((row >> 1) & 3)) * 8;
    aDst[rnd] = As + (size_t)idx * 8;
    bSrc[rnd] = Ubf + (size_t)(bx * 128 + row) * 2048 + half * 1024 + (c ^ ((row >> 1) & 3)) * 8;
    bDst[rnd] = Bs + (size_t)idx * 8;
  }

  int aOff[4], bOff[4];
#pragma unroll
  for (int mt = 0; mt < 4; ++mt) {
    int m = (wave & 1) * 64 + mt * 16 + lane15;
    aOff[mt] = m * 32 + (quad ^ ((m >> 1) & 3)) * 8;
  }
#pragma unroll
  for (int gt = 0; gt < 4; ++gt) {
    int g = (wave >> 1) * 64 + gt * 16 + lane15;
    bOff[gt] = g * 32 + (quad ^ ((g >> 1) & 3)) * 8;
  }

  const f32x4 zero4 = {0.f, 0.f, 0.f, 0.f};
  f32x4 acc[4][4];
#pragma unroll
  for (int mt = 0; mt < 4; ++mt)
#pragma unroll
    for (int gt = 0; gt < 4; ++gt) acc[mt][gt] = zero4;

  for (int ko = 0; ko < 1024; ko += 32) {
    __syncthreads();
#pragma unroll
    for (int rnd = 0; rnd < 2; ++rnd) {
      async16(aSrc[rnd] + ko, aDst[rnd]);
      async16(bSrc[rnd] + ko, bDst[rnd]);
    }
    __syncthreads();
    short8 af[4], bfr[4];
#pragma unroll
    for (int mt = 0; mt < 4; ++mt) af[mt] = *(const short8*)(As + aOff[mt]);
#pragma unroll
    for (int gt = 0; gt < 4; ++gt) bfr[gt] = *(const short8*)(Bs + bOff[gt]);
#pragma unroll
    for (int mt = 0; mt < 4; ++mt)
#pragma unroll
      for (int gt = 0; gt < 4; ++gt)
        acc[mt][gt] = __builtin_amdgcn_mfma_f32_16x16x32_bf16(af[mt], bfr[gt], acc[mt][gt], 0, 0, 0);
  }

  float bb[4];   // bias folded into half 0 only (PL + PR + b == PL' + PR')
#pragma unroll
  for (int gt = 0; gt < 4; ++gt)
    bb[gt] = (half == 0) ? bias[bx * 128 + (wave >> 1) * 64 + gt * 16 + lane15] : 0.f;

#pragma unroll
  for (int mt = 0; mt < 4; ++mt)
#pragma unroll
    for (int rg = 0; rg < 4; ++rg) {
      int row = (wave & 1) * 64 + mt * 16 + quad * 4 + rg;
      size_t pbase = (size_t)(half * 2048 + rt * 128 + row) * 5120 + bx * 128 + (wave >> 1) * 64;
#pragma unroll
      for (int gt = 0; gt < 4; ++gt)
        P[pbase + gt * 16 + lane15] = (_Float16)(acc[mt][gt][rg] + bb[gt]);
    }
}

// ---- fused: gather-add preact + gates + energy + softmax + combine ----
// Block = (step, b_local) via 1-D grid with XCD-affine b (flat&7).
// 512 thr = 8 waves; wave w handles rows a = t*8+w, lane owns cols l*16..+16.
// c -> LDS (permuted, 64KB); h -> 32 packed-bf16 VGPRs; h combined via
// cross-wave partial reduction through the reused LDS buffer.
__global__ __launch_bounds__(512, 4) void k_fused(
    const u16* __restrict__ chc, const _Float16* __restrict__ P,
    const int* __restrict__ ops, const float* __restrict__ eu,
    float* __restrict__ out, int bg)
{
  __shared__ u16 cS[32 * 1024];   // 64 KB; reused as float[8*1024] for h-reduce
  __shared__ float eS[32];

  const int tid = threadIdx.x;
  const int wave = tid >> 6, lane = tid & 63;
  const int flat = blockIdx.x;
  const int b_local = flat & 7;     // XCD-affine: same-XCD blocks share b
  const int step = flat >> 3;
  const int b = bg * 8 + b_local;

  float ureg[16];
  *(float4*)&ureg[0]  = *(const float4*)(eu + lane * 16);
  *(float4*)&ureg[4]  = *(const float4*)(eu + lane * 16 + 4);
  *(float4*)&ureg[8]  = *(const float4*)(eu + lane * 16 + 8);
  *(float4*)&ureg[12] = *(const float4*)(eu + lane * 16 + 12);
  float part = 0.f;
#pragma unroll
  for (int j = 0; j < 16; ++j) part += ureg[j] * ureg[j];
#pragma unroll
  for (int m = 1; m < 64; m <<= 1) part += __shfl_xor(part, m, 64);
  const float unorm = fmaxf(sqrtf(part), 1e-8f);

  u32 hPk[32];    // packed bf16 h: hPk[t*8 + sub*4 + (j>>1)] = cols (jj, jj+1)

  for (int t = 0; t < 4; ++t) {
    const int a = t * 8 + wave;
    const long opflat = (((long)step * 32 + b) * 32 + a) * 2;
    const int opL = ops[opflat], opR = ops[opflat + 1];
    const _Float16* PLp = P + (size_t)(b_local * 256 + opL) * 5120;
    const _Float16* PRp = P + (size_t)(2048 + b_local * 256 + opR) * 5120;
    const u16* ccLr = chc + (size_t)(b * 256 + opL) * 1024;
    const u16* ccRr = chc + (size_t)(b * 256 + opR) * 1024;
    float dot = 0.f, nn = 0.f;
#pragma unroll
    for (int sub = 0; sub < 2; ++sub) {
      const int g8 = lane * 16 + sub * 8;
      h8 pre[5];
#pragma unroll
      for (int q = 0; q < 5; ++q)
        pre[q] = *(const h8*)(PLp + q * 1024 + g8) + *(const h8*)(PRp + q * 1024 + g8);
      const u16x8 cl = *(const u16x8*)(ccLr + g8);
      const u16x8 cr = *(const u16x8*)(ccRr + g8);
      u16x8 co;
      u32 lo = 0;
#pragma unroll
      for (int j = 0; j < 8; ++j) {
        const int jj = sub * 8 + j;
        float pi  = (float)pre[0][j];
        float pfL = (float)pre[1][j];
        float pfR = (float)pre[2][j];
        float po  = (float)pre[3][j];
        float pu  = (float)pre[4][j];
        float cv = fast_sigmoid(pfL) * bf2f(cl[j]) + fast_sigmoid(pfR) * bf2f(cr[j])
                 + fast_sigmoid(pi) * fast_tanh(pu);
        float hv = fast_sigmoid(po) * fast_tanh(cv);
        co[j] = f2bf(cv);
        if ((j & 1) == 0) lo = (u32)f2bf(hv);
        else hPk[t * 8 + sub * 4 + (j >> 1)] = lo | ((u32)f2bf(hv) << 16);
        dot += hv * ureg[jj];
        nn  += hv * hv;
      }
      *(u16x8*)(cS + a * 1024 + sub * 512 + lane * 8) = co;  // permuted, b128
    }
#pragma unroll
    for (int m = 1; m < 64; m <<= 1) {
      dot += __shfl_xor(dot, m, 64);
      nn  += __shfl_xor(nn, m, 64);
    }
    if (lane == 0) eS[a] = dot / (unorm * fmaxf(sqrtf(nn), 1e-8f));
  }
  __syncthreads();

  // softmax over 32 (from LDS broadcast reads)
  float w[32];
  float mx = -1e30f;
#pragma unroll
  for (int a = 0; a < 32; ++a) mx = fmaxf(mx, eS[a]);
  float S = 0.f;
#pragma unroll
  for (int a = 0; a < 32; ++a) { w[a] = __expf(eS[a] - mx); S += w[a]; }
  const float inv = 1.0f / S;

  // c combine: thread owns cols g0,g0+1; u32 column reads (2-way, free)
  const int g0 = tid * 2;
  const int p = ((g0 >> 3) & 1) * 512 + (g0 >> 4) * 8 + (g0 & 7);
  float sc0 = 0.f, sc1 = 0.f;
#pragma unroll
  for (int a = 0; a < 32; ++a) {
    const u32 cv = *(const u32*)(cS + a * 1024 + p);
    sc0 += w[a] * __uint_as_float(cv << 16);
    sc1 += w[a] * __uint_as_float(cv & 0xffff0000u);
  }
  float* orow = out + ((size_t)b * CHART_ROWS + 256 + step) * 2048;
  *(float2*)(orow + g0) = make_float2(sc0 * inv, sc1 * inv);
  __syncthreads();            // all cS reads done; buffer reused below

  // h partials: thread sums its 4 a-rows for its 16 cols, stash to LDS
  float* rS = (float*)cS;     // [wave][1024] floats, swizzled for b128 writes
  float ph[16];
#pragma unroll
  for (int jj = 0; jj < 16; ++jj) ph[jj] = 0.f;
#pragma unroll
  for (int t = 0; t < 4; ++t) {
    const float wa = w[t * 8 + wave];
#pragma unroll
    for (int k = 0; k < 8; ++k) {
      const u32 pk2 = hPk[t * 8 + k];
      const int jj0 = (k >> 2) * 8 + (k & 3) * 2;
      ph[jj0]     += wa * __uint_as_float(pk2 << 16);
      ph[jj0 + 1] += wa * __uint_as_float(pk2 & 0xffff0000u);
    }
  }
#pragma unroll
  for (int s = 0; s < 4; ++s) {
    float4 v = make_float4(ph[s * 4], ph[s * 4 + 1], ph[s * 4 + 2], ph[s * 4 + 3]);
    // col g = l*16 + s*4 + k stored at word wave*1024 + s*256 + l*4 + k
    *(float4*)(rS + wave * 1024 + s * 256 + lane * 4) = v;   // lane-contiguous
  }
  __syncthreads();

  // reduce 8 wave-partials for cols g0,g0+1
  const int l_own = g0 >> 4, s_ = (g0 >> 2) & 3, k_ = g0 & 3;
  float sh0 = 0.f, sh1 = 0.f;
#pragma unroll
  for (int w8 = 0; w8 < 8; ++w8) {
    const float2 v = *(const float2*)(rS + w8 * 1024 + s_ * 256 + l_own * 4 + k_);
    sh0 += v.x; sh1 += v.y;
  }
  *(float2*)(orow + 1024 + g0) = make_float2(sh0 * inv, sh1 * inv);
}

extern "C" void kernel_launch(void* const* d_in, const int* in_sizes, int n_in,
                              void* d_out, int out_size, void* d_ws, size_t ws_size,
                              hipStream_t stream) {
  (void)in_sizes; (void)n_in; (void)out_size; (void)ws_size;
  const float* chart = (const float*)d_in[0];
  const int*   ops   = (const int*)d_in[1];
  // d_in[2] = start_index (256, hard-coded)
  const float* U     = (const float*)d_in[3];
  const float* bias  = (const float*)d_in[4];
  const float* eu    = (const float*)d_in[5];
  float* out = (float*)d_out;
  char* ws = (char*)d_ws;

  u16*      Ubf = (u16*)ws;                       // 20,971,520 B
  u16*      chb = (u16*)(ws + 20971520);          // 16,777,216 B
  u16*      chc = (u16*)(ws + 37748736);          // 16,777,216 B
  _Float16* P   = (_Float16*)(ws + 54525952);     // 41,943,040 B -> total 96,468,992 B

  k_cvt_u<<<10240, 256, 0, stream>>>((const float4*)U, Ubf);
  k_cvt_chart<<<8192, 256, 0, stream>>>(chart, chb, chc, out);

  for (int bg = 0; bg < 4; ++bg) {                  // 8 batches per group
    k_gemm_p<<<dim3(40, 32), 256, 0, stream>>>(chb, Ubf, bias, P, bg);
    k_fused<<<1024, 512, 0, stream>>>(chc, P, ops, eu, out, bg);
  }
}